// Round 2
// baseline (336.720 us; speedup 1.0000x reference)
//
#include <hip/hip_runtime.h>
#include <hip/hip_bf16.h>
#include <stdint.h>

// ---------------------------------------------------------------------------
// Round 2: structural rework.
//  - Linearity: scatter h (pre-W_c2) into S[N,128] (packed bf16x2 atomics),
//    move W_c2 GEMM to node level:  out[hi] += h@W_c2  ==  S@W_c2 at nodes.
//  - k_edge: weights resident in LDS (W_d2, W_c1_top), 12 waves/block,
//    wave-private QCC/act buffers, NO barriers in the main loop; grid-stride
//    over 16-edge tiles. 160KB LDS, 1 block/CU.
//  - k_final fuses agts@W_a + S@W_c2 -> gn -> relu -> @W_l -> gn -> +res relu.
// ---------------------------------------------------------------------------

typedef __bf16 bfx8 __attribute__((ext_vector_type(8)));
typedef float f32x4 __attribute__((ext_vector_type(4)));
typedef short s16x2 __attribute__((ext_vector_type(2)));

__device__ __forceinline__ unsigned short f2bfu(float f) {
  unsigned u = __builtin_bit_cast(unsigned, f);
  return (unsigned short)((u + 0x7fffu + ((u >> 16) & 1u)) >> 16);
}
__device__ __forceinline__ float bfu2f(unsigned short u) {
  return __builtin_bit_cast(float, ((unsigned)u) << 16);
}
__device__ __forceinline__ unsigned pk2(unsigned x, unsigned y) {
  float lo = bfu2f((unsigned short)(x & 0xffffu)) + bfu2f((unsigned short)(y & 0xffffu));
  float hi = bfu2f((unsigned short)(x >> 16)) + bfu2f((unsigned short)(y >> 16));
  return (unsigned)f2bfu(lo) | ((unsigned)f2bfu(hi) << 16);
}

// packed bf16x2 atomic add into global memory
__device__ __forceinline__ void atomAddBf2(unsigned short* p, unsigned v) {
#if defined(__has_builtin) && __has_builtin(__builtin_amdgcn_global_atomic_fadd_v2bf16)
  __builtin_amdgcn_global_atomic_fadd_v2bf16(
      (__attribute__((address_space(1))) s16x2*)p, __builtin_bit_cast(s16x2, v));
#else
  unsigned* q = (unsigned*)p;
  unsigned old = *q;
  while (true) {
    unsigned nv = pk2(old, v);
    unsigned prev = atomicCAS(q, old, nv);
    if (prev == old) break;
    old = prev;
  }
#endif
}

// swizzled byte offset of element (row, kbyte) in a [rows][128] bf16 LDS tile
__device__ __forceinline__ int swzb(int row, int kbyte) {
  return (row * 256 + kbyte) ^ ((row & 7) << 4);
}

// linear copy of one pre-swizzled transposed weight (32768 B) into LDS
__device__ __forceinline__ void stage_w(const unsigned short* wsrc, char* dst, int tid, int nth) {
  const uint4* s = (const uint4*)wsrc;
  uint4* d = (uint4*)dst;
  for (int i = tid; i < 2048; i += nth) d[i] = s[i];
}

// wave GEMM: [16 rows x 128] @ [128 x 128] -> acc[8] tiles (16x16), accumulate
template <bool A_FROM_LDS>
__device__ __forceinline__ void wave_gemm(const char* WtL, const char* XL,
                                          const bfx8* aF, f32x4 acc[8],
                                          int lg, int lr) {
#pragma unroll
  for (int ks = 0; ks < 4; ++ks) {
    bfx8 a;
    if (A_FROM_LDS)
      a = *(const bfx8*)(XL + swzb(lr, (ks * 32 + lg * 8) * 2));
    else
      a = aF[ks];
#pragma unroll
    for (int t = 0; t < 8; ++t) {
      int n = t * 16 + lr;
      bfx8 b = *(const bfx8*)(WtL + swzb(n, (ks * 32 + lg * 8) * 2));
      acc[t] = __builtin_amdgcn_mfma_f32_16x16x32_bf16(a, b, acc[t], 0, 0, 0);
    }
  }
}

// in-register GroupNorm(1 group over 128 ch) on C-layout accumulators
__device__ __forceinline__ void wave_gn(f32x4 acc[8], const float* g, const float* b,
                                        int lg, int lr, bool do_relu) {
  float s0 = 0.f, s1 = 0.f, s2 = 0.f, s3 = 0.f;
  float q0 = 0.f, q1 = 0.f, q2 = 0.f, q3 = 0.f;
#pragma unroll
  for (int t = 0; t < 8; ++t) {
    float v0 = acc[t][0], v1 = acc[t][1], v2 = acc[t][2], v3 = acc[t][3];
    s0 += v0; q0 += v0 * v0;
    s1 += v1; q1 += v1 * v1;
    s2 += v2; q2 += v2 * v2;
    s3 += v3; q3 += v3 * v3;
  }
#pragma unroll
  for (int m = 1; m <= 8; m <<= 1) {
    s0 += __shfl_xor(s0, m, 64); q0 += __shfl_xor(q0, m, 64);
    s1 += __shfl_xor(s1, m, 64); q1 += __shfl_xor(q1, m, 64);
    s2 += __shfl_xor(s2, m, 64); q2 += __shfl_xor(q2, m, 64);
    s3 += __shfl_xor(s3, m, 64); q3 += __shfl_xor(q3, m, 64);
  }
  float gc[8], bc[8];
#pragma unroll
  for (int t = 0; t < 8; ++t) { gc[t] = g[t * 16 + lr]; bc[t] = b[t * 16 + lr]; }
  float mean[4], rstd[4];
  {
    const float inv = 1.f / 128.f;
    float m0 = s0 * inv, m1 = s1 * inv, m2 = s2 * inv, m3 = s3 * inv;
    mean[0] = m0; mean[1] = m1; mean[2] = m2; mean[3] = m3;
    rstd[0] = rsqrtf(q0 * inv - m0 * m0 + 1e-5f);
    rstd[1] = rsqrtf(q1 * inv - m1 * m1 + 1e-5f);
    rstd[2] = rsqrtf(q2 * inv - m2 * m2 + 1e-5f);
    rstd[3] = rsqrtf(q3 * inv - m3 * m3 + 1e-5f);
  }
#pragma unroll
  for (int t = 0; t < 8; ++t) {
#pragma unroll
    for (int r = 0; r < 4; ++r) {
      float v = (acc[t][r] - mean[r]) * rstd[r] * gc[t] + bc[t];
      if (do_relu) v = fmaxf(v, 0.f);
      acc[t][r] = v;
    }
  }
}

// write post-GN tile (C-layout) into wave-private swizzled LDS stage as bf16
__device__ __forceinline__ void wave_stage(char* XL, const f32x4 acc[8], int lg, int lr) {
#pragma unroll
  for (int t = 0; t < 8; ++t) {
#pragma unroll
    for (int r = 0; r < 4; ++r) {
      int row = 4 * lg + r, c = t * 16 + lr;
      *(unsigned short*)(XL + swzb(row, 2 * c)) = f2bfu(acc[t][r]);
    }
  }
}

// ---------------------------------------------------------------------------
// prep: transpose + bf16-convert + pre-swizzle the 8 [128x128] weights
// order: 0 W_d2, 1 W_c1_top, 2 W_c1_mid, 3 W_c1_bot, 4 W_c2, 5 W_q, 6 W_a, 7 W_l
// ---------------------------------------------------------------------------
__global__ void k_prep_weights(const float* Wd2, const float* Wc1, const float* Wc2,
                               const float* Wq, const float* Wa, const float* Wl,
                               unsigned short* wsW) {
  __shared__ unsigned short tmp[128 * 128];
  int m = blockIdx.x;
  const float* src;
  switch (m) {
    case 0: src = Wd2; break;
    case 1: src = Wc1; break;
    case 2: src = Wc1 + 128 * 128; break;
    case 3: src = Wc1 + 256 * 128; break;
    case 4: src = Wc2; break;
    case 5: src = Wq; break;
    case 6: src = Wa; break;
    default: src = Wl; break;
  }
  int tid = threadIdx.x;
#pragma unroll
  for (int i = 0; i < 16; ++i) {
    int lin = i * 256 + tid;
    float4 v = ((const float4*)src)[lin];
    ushort4 b;
    b.x = f2bfu(v.x); b.y = f2bfu(v.y); b.z = f2bfu(v.z); b.w = f2bfu(v.w);
    *(ushort4*)&tmp[lin * 4] = b;
  }
  __syncthreads();
  unsigned short* dst = wsW + (size_t)m * 16384;
#pragma unroll
  for (int i = 0; i < 16; ++i) {
    int lin = i * 256 + tid;
    int n = lin >> 5, q = lin & 31, k0 = q * 4;
    ushort4 b;
    b.x = tmp[(k0 + 0) * 128 + n];
    b.y = tmp[(k0 + 1) * 128 + n];
    b.z = tmp[(k0 + 2) * 128 + n];
    b.w = tmp[(k0 + 3) * 128 + n];
    *(ushort4*)((char*)dst + swzb(n, k0 * 2)) = b;
  }
}

// ---------------------------------------------------------------------------
// ctx precompute: CC = ctx @ W_c1_bot (bf16)
// ---------------------------------------------------------------------------
__global__ __launch_bounds__(256, 2) void k_ctx(const float* ctx, const unsigned short* wsW,
                                                unsigned short* cc, int M) {
  __shared__ __align__(16) char lds[32768];
  int tid = threadIdx.x, wid = tid >> 6, lane = tid & 63, lg = lane >> 4, lr = lane & 15;
  int base = blockIdx.x * 64;
  stage_w(wsW + 3 * 16384, lds, tid, 256);
  int row = base + 16 * wid + lr;
  int rload = row < M ? row : M - 1;
  bfx8 cf[4];
#pragma unroll
  for (int ks = 0; ks < 4; ++ks) {
    int k0 = ks * 32 + lg * 8;
    const float4* p = (const float4*)&ctx[(size_t)rload * 128 + k0];
    float4 a = p[0], b = p[1];
    bfx8 f;
    f[0] = (__bf16)a.x; f[1] = (__bf16)a.y; f[2] = (__bf16)a.z; f[3] = (__bf16)a.w;
    f[4] = (__bf16)b.x; f[5] = (__bf16)b.y; f[6] = (__bf16)b.z; f[7] = (__bf16)b.w;
    cf[ks] = f;
  }
  __syncthreads();
  f32x4 acc[8];
#pragma unroll
  for (int t = 0; t < 8; ++t) acc[t] = 0.f;
  wave_gemm<false>(lds, nullptr, cf, acc, lg, lr);
#pragma unroll
  for (int r = 0; r < 4; ++r) {
    int grow = base + 16 * wid + 4 * lg + r;
    if (grow < M) {
#pragma unroll
      for (int t = 0; t < 8; ++t)
        cc[(size_t)grow * 128 + t * 16 + lr] = f2bfu(acc[t][r]);
    }
  }
}

// ---------------------------------------------------------------------------
// agent precompute: QC = relu(gn(agts@W_q))@W_c1_mid (bf16)
// resident weights, 12 waves, grid-stride, no in-loop barriers
// ---------------------------------------------------------------------------
__global__ __launch_bounds__(768, 3) void k_agents(const float* agts, const float* g_q,
                                                   const float* b_q, const unsigned short* wsW,
                                                   unsigned short* qc, int N) {
  __shared__ __align__(16) char lds[114688];
  char* WqL = lds;
  char* WcL = lds + 32768;
  int tid = threadIdx.x, wid = tid >> 6, lane = tid & 63, lg = lane >> 4, lr = lane & 15;
  char* actL = lds + 65536 + wid * 4096;
  stage_w(wsW + 5 * 16384, WqL, tid, 768);
  stage_w(wsW + 2 * 16384, WcL, tid, 768);
  __syncthreads();
  int nTiles = (N + 15) >> 4;
  int stride = gridDim.x * 12;
  for (int tile = blockIdx.x * 12 + wid; tile < nTiles; tile += stride) {
    int base = tile << 4;
    int row = base + lr; if (row >= N) row = N - 1;
    bfx8 af[4];
#pragma unroll
    for (int ks = 0; ks < 4; ++ks) {
      int k0 = ks * 32 + lg * 8;
      const float4* p = (const float4*)&agts[(size_t)row * 128 + k0];
      float4 a = p[0], b = p[1];
      bfx8 f;
      f[0] = (__bf16)a.x; f[1] = (__bf16)a.y; f[2] = (__bf16)a.z; f[3] = (__bf16)a.w;
      f[4] = (__bf16)b.x; f[5] = (__bf16)b.y; f[6] = (__bf16)b.z; f[7] = (__bf16)b.w;
      af[ks] = f;
    }
    f32x4 acc[8];
#pragma unroll
    for (int t = 0; t < 8; ++t) acc[t] = 0.f;
    wave_gemm<false>(WqL, nullptr, af, acc, lg, lr);
    wave_gn(acc, g_q, b_q, lg, lr, true);
    wave_stage(actL, acc, lg, lr);
#pragma unroll
    for (int t = 0; t < 8; ++t) acc[t] = 0.f;
    wave_gemm<true>(WcL, actL, nullptr, acc, lg, lr);
#pragma unroll
    for (int r = 0; r < 4; ++r) {
      int grow = base + 4 * lg + r;
      if (grow < N) {
#pragma unroll
        for (int t = 0; t < 8; ++t)
          qc[(size_t)grow * 128 + t * 16 + lr] = f2bfu(acc[t][r]);
      }
    }
  }
}

// ---------------------------------------------------------------------------
// edge kernel: per 16-edge wave-tile: d1 -> W_d2/gn -> (+QC[hi]+CC[wi]) @
// W_c1_top/gn -> scatter h into S via packed bf16x2 atomics.
// Weights resident; zero barriers in the loop.
// ---------------------------------------------------------------------------
__global__ __launch_bounds__(768, 3) void k_edge(
    const float* agt_ctrs, const float* ctx_ctrs, const int* hi, const int* wi,
    const float* W_d1, const float* b_d1, const float* g_d2, const float* b_d2,
    const float* g_c1, const float* b_c1, const unsigned short* wsW,
    const unsigned short* qc, const unsigned short* cc, unsigned short* S, int E) {
  __shared__ __align__(16) char lds[163840];
  char* Wd2L = lds;
  char* Wc1L = lds + 32768;
  int tid = threadIdx.x, wid = tid >> 6, lane = tid & 63, lg = lane >> 4, lr = lane & 15;
  char* QCCL = lds + 65536 + wid * 8192;
  char* actL = QCCL + 4096;
  stage_w(wsW + 0 * 16384, Wd2L, tid, 768);
  stage_w(wsW + 1 * 16384, Wc1L, tid, 768);
  __syncthreads();
  int nTiles = (E + 15) >> 4;
  int stride = gridDim.x * 12;
  for (int tile = blockIdx.x * 12 + wid; tile < nTiles; tile += stride) {
    int base = tile << 4;
    // ---- wave-private QCC gather: QCC[r][c] = QC[hi[base+r]][c] + CC[wi[base+r]][c]
    {
      int gr = lane >> 2, gq = lane & 3;
      int ge = base + gr; if (ge >= E) ge = E - 1;
      int gh = hi[ge], gw2 = wi[ge];
      const uint4* qrow = (const uint4*)(qc + (size_t)gh * 128) + gq * 4;
      const uint4* crow = (const uint4*)(cc + (size_t)gw2 * 128) + gq * 4;
#pragma unroll
      for (int i = 0; i < 4; ++i) {
        uint4 av = qrow[i], bv = crow[i];
        uint4 o;
        o.x = pk2(av.x, bv.x); o.y = pk2(av.y, bv.y);
        o.z = pk2(av.z, bv.z); o.w = pk2(av.w, bv.w);
        *(uint4*)(QCCL + swzb(gr, gq * 64 + i * 16)) = o;
      }
    }
    // ---- d1 = relu(dist @ W_d1 + b_d1), built directly in A-fragment layout
    bfx8 d1f[4];
    {
      int e1 = base + lr; if (e1 >= E) e1 = E - 1;
      int h1 = hi[e1], w1 = wi[e1];
      float dx = agt_ctrs[2 * h1] - ctx_ctrs[2 * w1];
      float dy = agt_ctrs[2 * h1 + 1] - ctx_ctrs[2 * w1 + 1];
#pragma unroll
      for (int ks = 0; ks < 4; ++ks) {
        int k0 = ks * 32 + lg * 8;
        const float4* w0 = (const float4*)&W_d1[k0];
        const float4* w1p = (const float4*)&W_d1[128 + k0];
        const float4* bp = (const float4*)&b_d1[k0];
        float4 w0a = w0[0], w0b = w0[1];
        float4 w1a = w1p[0], w1b = w1p[1];
        float4 ba = bp[0], bb = bp[1];
        bfx8 f;
        f[0] = (__bf16)fmaxf(dx * w0a.x + dy * w1a.x + ba.x, 0.f);
        f[1] = (__bf16)fmaxf(dx * w0a.y + dy * w1a.y + ba.y, 0.f);
        f[2] = (__bf16)fmaxf(dx * w0a.z + dy * w1a.z + ba.z, 0.f);
        f[3] = (__bf16)fmaxf(dx * w0a.w + dy * w1a.w + ba.w, 0.f);
        f[4] = (__bf16)fmaxf(dx * w0b.x + dy * w1b.x + bb.x, 0.f);
        f[5] = (__bf16)fmaxf(dx * w0b.y + dy * w1b.y + bb.y, 0.f);
        f[6] = (__bf16)fmaxf(dx * w0b.z + dy * w1b.z + bb.z, 0.f);
        f[7] = (__bf16)fmaxf(dx * w0b.w + dy * w1b.w + bb.w, 0.f);
        d1f[ks] = f;
      }
    }
    f32x4 acc[8];
#pragma unroll
    for (int t = 0; t < 8; ++t) acc[t] = 0.f;
    wave_gemm<false>(Wd2L, nullptr, d1f, acc, lg, lr);   // d1 @ W_d2
    wave_gn(acc, g_d2, b_d2, lg, lr, true);
    wave_stage(actL, acc, lg, lr);
    // acc init = QC[hi] + CC[wi]
#pragma unroll
    for (int t = 0; t < 8; ++t) {
#pragma unroll
      for (int r = 0; r < 4; ++r)
        acc[t][r] = bfu2f(*(const unsigned short*)(QCCL + swzb(4 * lg + r, 2 * (16 * t + lr))));
    }
    wave_gemm<true>(Wc1L, actL, nullptr, acc, lg, lr);   // += d2 @ W_c1_top
    wave_gn(acc, g_c1, b_c1, lg, lr, true);              // h
    // ---- scatter h into S[hi] with packed bf16x2 atomics
    int hh[4], valid[4];
#pragma unroll
    for (int r = 0; r < 4; ++r) {
      int er = base + 4 * lg + r;
      valid[r] = er < E;
      hh[r] = hi[valid[r] ? er : 0];
    }
    bool evn = (lane & 1) == 0;
#pragma unroll
    for (int t = 0; t < 8; ++t) {
      bool mine = evn ? (t < 4) : (t >= 4);
#pragma unroll
      for (int r = 0; r < 4; ++r) {
        float v = acc[t][r];
        float vx = __shfl_xor(v, 1, 64);
        if (mine && valid[r]) {
          unsigned pkv = evn ? ((unsigned)f2bfu(v) | ((unsigned)f2bfu(vx) << 16))
                             : ((unsigned)f2bfu(vx) | ((unsigned)f2bfu(v) << 16));
          int col = (16 * t + lr) & ~1;
          atomAddBf2(S + (size_t)hh[r] * 128 + col, pkv);
        }
      }
    }
  }
}

// ---------------------------------------------------------------------------
// final: a = agts@W_a + S@W_c2; a = relu(gn(a,g_n,b_n)); a = gn(a@W_l,g_l,b_l);
// out = relu(a + agts)
// ---------------------------------------------------------------------------
__global__ __launch_bounds__(768, 3) void k_final(const float* agts, const float* g_n,
                                                  const float* b_n, const float* g_l,
                                                  const float* b_l, const unsigned short* wsW,
                                                  const unsigned short* S, float* out, int N) {
  __shared__ __align__(16) char lds[147456];
  char* WaL = lds;
  char* Wc2L = lds + 32768;
  char* WlL = lds + 65536;
  int tid = threadIdx.x, wid = tid >> 6, lane = tid & 63, lg = lane >> 4, lr = lane & 15;
  char* actL = lds + 98304 + wid * 4096;
  stage_w(wsW + 6 * 16384, WaL, tid, 768);
  stage_w(wsW + 4 * 16384, Wc2L, tid, 768);
  stage_w(wsW + 7 * 16384, WlL, tid, 768);
  __syncthreads();
  int nTiles = (N + 15) >> 4;
  int stride = gridDim.x * 12;
  for (int tile = blockIdx.x * 12 + wid; tile < nTiles; tile += stride) {
    int base = tile << 4;
    int row = base + lr; if (row >= N) row = N - 1;
    bfx8 af[4], sf[4];
#pragma unroll
    for (int ks = 0; ks < 4; ++ks) {
      int k0 = ks * 32 + lg * 8;
      const float4* p = (const float4*)&agts[(size_t)row * 128 + k0];
      float4 a = p[0], b = p[1];
      bfx8 f;
      f[0] = (__bf16)a.x; f[1] = (__bf16)a.y; f[2] = (__bf16)a.z; f[3] = (__bf16)a.w;
      f[4] = (__bf16)b.x; f[5] = (__bf16)b.y; f[6] = (__bf16)b.z; f[7] = (__bf16)b.w;
      af[ks] = f;
      sf[ks] = *(const bfx8*)&S[(size_t)row * 128 + k0];
    }
    f32x4 acc[8];
#pragma unroll
    for (int t = 0; t < 8; ++t) acc[t] = 0.f;
    wave_gemm<false>(WaL, nullptr, af, acc, lg, lr);   // agts @ W_a
    wave_gemm<false>(Wc2L, nullptr, sf, acc, lg, lr);  // + S @ W_c2
    wave_gn(acc, g_n, b_n, lg, lr, true);
    wave_stage(actL, acc, lg, lr);
#pragma unroll
    for (int t = 0; t < 8; ++t) acc[t] = 0.f;
    wave_gemm<true>(WlL, actL, nullptr, acc, lg, lr);  // @ W_l
    wave_gn(acc, g_l, b_l, lg, lr, false);
#pragma unroll
    for (int r = 0; r < 4; ++r) {
      int grow = base + 4 * lg + r;
      if (grow < N) {
#pragma unroll
        for (int t = 0; t < 8; ++t) {
          int c = t * 16 + lr;
          float res = agts[(size_t)grow * 128 + c];
          out[(size_t)grow * 128 + c] = fmaxf(acc[t][r] + res, 0.f);
        }
      }
    }
  }
}

// ---------------------------------------------------------------------------
extern "C" void kernel_launch(void* const* d_in, const int* in_sizes, int n_in,
                              void* d_out, int out_size, void* d_ws, size_t ws_size,
                              hipStream_t stream) {
  const float* agts = (const float*)d_in[0];
  const float* ctx = (const float*)d_in[1];
  const float* agt_ctrs = (const float*)d_in[2];
  const float* ctx_ctrs = (const float*)d_in[3];
  const int* hi = (const int*)d_in[4];
  const int* wi = (const int*)d_in[5];
  const float* W_d1 = (const float*)d_in[6];
  const float* b_d1 = (const float*)d_in[7];
  const float* W_d2 = (const float*)d_in[8];
  const float* g_d2 = (const float*)d_in[9];
  const float* b_d2 = (const float*)d_in[10];
  const float* W_q = (const float*)d_in[11];
  const float* g_q = (const float*)d_in[12];
  const float* b_q = (const float*)d_in[13];
  const float* W_c1 = (const float*)d_in[14];
  const float* g_c1 = (const float*)d_in[15];
  const float* b_c1 = (const float*)d_in[16];
  const float* W_c2 = (const float*)d_in[17];
  const float* W_a = (const float*)d_in[18];
  const float* g_n = (const float*)d_in[19];
  const float* b_n = (const float*)d_in[20];
  const float* W_l = (const float*)d_in[21];
  const float* g_l = (const float*)d_in[22];
  const float* b_l = (const float*)d_in[23];

  int N = in_sizes[0] / 128;
  int M = in_sizes[1] / 128;
  int E = in_sizes[4];

  float* out = (float*)d_out;
  char* ws = (char*)d_ws;
  unsigned short* qcP = (unsigned short*)ws;                              // N*256 B
  unsigned short* ccP = (unsigned short*)(ws + (size_t)N * 256);          // M*256 B
  unsigned short* Sp = (unsigned short*)(ws + (size_t)N * 256 + (size_t)M * 256);  // N*256 B
  unsigned short* wsW = (unsigned short*)(ws + (size_t)N * 512 + (size_t)M * 256); // 256 KB

  hipMemsetAsync(Sp, 0, (size_t)N * 256, stream);
  k_prep_weights<<<8, 256, 0, stream>>>(W_d2, W_c1, W_c2, W_q, W_a, W_l, wsW);
  k_ctx<<<(M + 63) / 64, 256, 0, stream>>>(ctx, wsW, ccP, M);
  k_agents<<<256, 768, 0, stream>>>(agts, g_q, b_q, wsW, qcP, N);
  k_edge<<<256, 768, 0, stream>>>(agt_ctrs, ctx_ctrs, hi, wi, W_d1, b_d1,
                                  g_d2, b_d2, g_c1, b_c1, wsW, qcP, ccP, Sp, E);
  k_final<<<256, 768, 0, stream>>>(agts, g_n, b_n, g_l, b_l, wsW, Sp, out, N);
}